// Round 13
// baseline (335.870 us; speedup 1.0000x reference)
//
#include <hip/hip_runtime.h>

#define N_NODES 100000
#define N_EDGES 1600000
#define N_FEAT  256
#define N_HID   64
#define N_CLS   16
#define NB      391          // ceil(N_NODES/256) row buckets
#define CHUNK   8192         // edges per scatter block (R12: 2048 hurt write-amp)
#define NSCAT   196          // ceil(N_EDGES/CHUNK) scatter blocks
#define NGEMM1  1563         // ceil(N_NODES/64) gemm1 blocks

typedef unsigned short bfraw;
typedef unsigned int uint32;

typedef __attribute__((ext_vector_type(8))) short  bf16x8;
typedef __attribute__((ext_vector_type(4))) float  f32x4;

__device__ __forceinline__ bfraw f2bf(float f) {   // RNE
    union { float f; unsigned int i; } v; v.f = f;
    unsigned int x = v.i;
    return (bfraw)((x + 0x7FFFu + ((x >> 16) & 1u)) >> 16);
}

// ---------------------------------------------------------------------------
// Merged: blocks [0,64) pack W1 into B-fragment-order bf16 table;
// blocks [64,320) histogram rows into 256-row buckets (LDS-staged).
// ---------------------------------------------------------------------------
__global__ __launch_bounds__(256) void w1cvt_hist_k(const float* __restrict__ W1,
                                                    bfraw* __restrict__ w1f,
                                                    const int* __restrict__ rowi,
                                                    int* __restrict__ bcnt) {
    __shared__ int lh[NB];
    if (blockIdx.x < 64) {
        int i = blockIdx.x * 256 + threadIdx.x;          // 16384 total
        int k = i >> 6, n = i & 63;
        w1f[((size_t)((k >> 3) * 64 + n) << 3) + (k & 7)] = f2bf(W1[i]);
        return;
    }
    for (int i = threadIdx.x; i < NB; i += 256) lh[i] = 0;
    __syncthreads();
    for (int e = (blockIdx.x - 64) * 256 + threadIdx.x; e < N_EDGES; e += 256 * 256)
        atomicAdd(&lh[rowi[e] >> 8], 1);
    __syncthreads();
    for (int i = threadIdx.x; i < NB; i += 256) {
        int c = lh[i];
        if (c) atomicAdd(&bcnt[i], c);
    }
}

// exclusive scan of NB bucket counts -> bbase[0..NB], cursors; rp[N]=E
__global__ __launch_bounds__(512) void bscan_k(const int* __restrict__ bcnt,
                                               int* __restrict__ bbase,
                                               int* __restrict__ gcur,
                                               int* __restrict__ rp) {
    __shared__ int s[512];
    int t = threadIdx.x;
    int v = (t < NB) ? bcnt[t] : 0;
    s[t] = v;
    __syncthreads();
    #pragma unroll
    for (int off = 1; off < 512; off <<= 1) {
        int x = (t >= off) ? s[t - off] : 0;
        __syncthreads();
        s[t] += x;
        __syncthreads();
    }
    if (t <= NB) {
        int b = s[t] - v;              // exclusive prefix (v=0 at t==NB)
        bbase[t] = b;
        if (t < NB) gcur[t] = b;
    }
    if (t == 0) rp[N_NODES] = N_EDGES;
}

// ---------------------------------------------------------------------------
// Merged dispatch: blocks [0,NSCAT) scatter edges into bucket regions;
// blocks [NSCAT, NSCAT+NGEMM1) run GEMM1 writing h0 in FP32 (spmm1 then
// gathers float4 per lane with zero unpack VALU).
// ---------------------------------------------------------------------------
__global__ __launch_bounds__(256) void scatter_gemm1_k(const int* __restrict__ rowi,
                                                       const int* __restrict__ coli,
                                                       const float* __restrict__ vals,
                                                       int* __restrict__ gcur,
                                                       int2* __restrict__ edges,
                                                       const float* __restrict__ x,
                                                       const bfraw* __restrict__ w1f,
                                                       const float* __restrict__ b1,
                                                       float* __restrict__ h0f) {
    __shared__ int lh[NB];
    __shared__ int lb[NB];
    const int t = threadIdx.x;

    if (blockIdx.x < NSCAT) {
        // ---------------- scatter path ----------------
        const int e0 = blockIdx.x * CHUNK;
        for (int i = t; i < NB; i += 256) lh[i] = 0;
        __syncthreads();
        for (int j = t; j < CHUNK; j += 256) {
            int e = e0 + j;
            if (e < N_EDGES) atomicAdd(&lh[rowi[e] >> 8], 1);
        }
        __syncthreads();
        for (int i = t; i < NB; i += 256) {
            int c = lh[i];
            lb[i] = c ? atomicAdd(&gcur[i], c) : 0;
            lh[i] = 0;                      // reuse as rank counter
        }
        __syncthreads();
        for (int j = t; j < CHUNK; j += 256) {
            int e = e0 + j;
            if (e < N_EDGES) {
                int r  = rowi[e];
                int b  = r >> 8;
                int rk = atomicAdd(&lh[b], 1);
                edges[lb[b] + rk] = make_int2(coli[e] | ((r & 255) << 17),
                                              __float_as_int(vals[e]));
            }
        }
        return;
    }

    // ---------------- gemm1 path (fp32 h0 output) ----------------
    const int bg   = blockIdx.x - NSCAT;
    const int w    = t >> 6;
    const int lane = t & 63;
    const int q    = lane >> 4;
    const int m    = lane & 15;

    const int row  = bg * 64 + w * 16 + m;
    const int srow = row < N_NODES ? row : N_NODES - 1;
    const float* xp = x + (size_t)srow * N_FEAT + q * 8;
    const bf16x8* w1v = (const bf16x8*)w1f;

    f32x4 acc[4];
    #pragma unroll
    for (int nt = 0; nt < 4; ++nt) acc[nt] = (f32x4){0.f, 0.f, 0.f, 0.f};

    #pragma unroll
    for (int s = 0; s < 8; ++s) {
        float4 a0 = *(const float4*)(xp + s * 32);
        float4 a1 = *(const float4*)(xp + s * 32 + 4);
        bf16x8 af;
        af[0] = (short)f2bf(a0.x); af[1] = (short)f2bf(a0.y);
        af[2] = (short)f2bf(a0.z); af[3] = (short)f2bf(a0.w);
        af[4] = (short)f2bf(a1.x); af[5] = (short)f2bf(a1.y);
        af[6] = (short)f2bf(a1.z); af[7] = (short)f2bf(a1.w);
        const int g = s * 4 + q;                 // k-group (k = g*8)
        #pragma unroll
        for (int nt = 0; nt < 4; ++nt) {
            bf16x8 bf_ = w1v[g * 64 + nt * 16 + m];
            acc[nt] = __builtin_amdgcn_mfma_f32_16x16x32_bf16(af, bf_, acc[nt], 0, 0, 0);
        }
    }

    float bb[4];
    #pragma unroll
    for (int nt = 0; nt < 4; ++nt) bb[nt] = b1[nt * 16 + m];

    const int orow0 = bg * 64 + w * 16 + q * 4;
    #pragma unroll
    for (int r = 0; r < 4; ++r) {
        int orow = orow0 + r;
        if (orow < N_NODES) {
            float* op = h0f + (size_t)orow * N_HID + m;
            #pragma unroll
            for (int nt = 0; nt < 4; ++nt)
                op[nt * 16] = acc[nt][r] + bb[nt];
        }
    }
}

// ---------------------------------------------------------------------------
// Per-bucket counting sort -> exact CSR (edges2, rp). One block per bucket.
// ---------------------------------------------------------------------------
__global__ __launch_bounds__(256) void sort_k(const int* __restrict__ bbase,
                                              const int2* __restrict__ edges,
                                              int2* __restrict__ edges2,
                                              int* __restrict__ rp) {
    __shared__ int cnt[256];
    __shared__ int pos[256];
    const int t   = threadIdx.x;
    const int b   = blockIdx.x;
    const int beg = bbase[b];
    const int end = bbase[b + 1];

    cnt[t] = 0;
    __syncthreads();
    for (int i = beg + t; i < end; i += 256)
        atomicAdd(&cnt[(edges[i].x >> 17) & 255], 1);
    __syncthreads();

    int v = cnt[t];
    pos[t] = v;
    __syncthreads();
    #pragma unroll
    for (int off = 1; off < 256; off <<= 1) {
        int y = (t >= off) ? pos[t - off] : 0;
        __syncthreads();
        pos[t] += y;
        __syncthreads();
    }
    int excl = pos[t] - v;

    int row = (b << 8) + t;
    if (row < N_NODES) rp[row] = beg + excl;
    __syncthreads();
    pos[t] = excl;                             // cursor
    __syncthreads();

    for (int i = beg + t; i < end; i += 256) {
        int2 E = edges[i];
        int r  = (E.x >> 17) & 255;
        int rk = atomicAdd(&pos[r], 1);
        edges2[beg + rk] = make_int2(E.x & 0x1FFFF, E.y);
    }
}

// ---------------------------------------------------------------------------
// SpMM1 (CSR) fused with ReLU + GEMM2: one 16-lane group per row,
// 16 rows per block. Lane l gathers float4 (features 4l..4l+3, FP32 h0)
// per edge -- zero unpack VALU. 8 edges in flight per group.
// Epilogue: relu'd 16x64 tile in LDS, 256 threads compute tile @ W2 + b2.
// ---------------------------------------------------------------------------
__global__ __launch_bounds__(256) void spmm1_fused3_k(const int* __restrict__ rp,
                                                      const int2* __restrict__ edges2,
                                                      const float* __restrict__ h0f,
                                                      const float* __restrict__ W2,
                                                      const float* __restrict__ b2,
                                                      float* __restrict__ h2) {
    __shared__ float Hs[16][68];       // stride 68: float4-aligned rows, 2-way banks
    __shared__ float Ws[64 * 16];
    __shared__ float bs[16];
    const int t = threadIdx.x;
    *(float4*)&Ws[t * 4] = ((const float4*)W2)[t];
    if (t < 16) bs[t] = b2[t];

    const int g16 = t >> 4;            // group id = row within block
    const int l   = t & 15;            // lane in group: owns features 4l..4l+3
    const int row = blockIdx.x * 16 + g16;
    const int beg = rp[row];
    const int end = rp[row + 1];

    const float4* h0v = (const float4*)h0f;  // 16B = features 4l..4l+3

    float a0 = 0.f, a1 = 0.f, a2 = 0.f, a3 = 0.f;
    int i = beg;
    for (; i + 8 <= end; i += 8) {
        int2 E[8];
        #pragma unroll
        for (int u = 0; u < 8; ++u) E[u] = edges2[i + u];
        float4 q[8];
        #pragma unroll
        for (int u = 0; u < 8; ++u) q[u] = h0v[(size_t)E[u].x * 16 + l];
        #pragma unroll
        for (int u = 0; u < 8; ++u) {
            float v = __int_as_float(E[u].y);
            a0 += v * q[u].x; a1 += v * q[u].y;
            a2 += v * q[u].z; a3 += v * q[u].w;
        }
    }
    for (; i + 4 <= end; i += 4) {
        int2 E[4];
        #pragma unroll
        for (int u = 0; u < 4; ++u) E[u] = edges2[i + u];
        float4 q[4];
        #pragma unroll
        for (int u = 0; u < 4; ++u) q[u] = h0v[(size_t)E[u].x * 16 + l];
        #pragma unroll
        for (int u = 0; u < 4; ++u) {
            float v = __int_as_float(E[u].y);
            a0 += v * q[u].x; a1 += v * q[u].y;
            a2 += v * q[u].z; a3 += v * q[u].w;
        }
    }
    for (; i < end; ++i) {
        int2 E = edges2[i];
        float4 q = h0v[(size_t)E.x * 16 + l];
        float v = __int_as_float(E.y);
        a0 += v * q.x; a1 += v * q.y;
        a2 += v * q.z; a3 += v * q.w;
    }

    *(float4*)&Hs[g16][4 * l] = make_float4(fmaxf(a0, 0.f), fmaxf(a1, 0.f),
                                            fmaxf(a2, 0.f), fmaxf(a3, 0.f));
    __syncthreads();

    // epilogue: h2[16][16] = Hs @ W2 + b2
    const int r = t >> 4;
    const int c = t & 15;
    float a = bs[c];
    #pragma unroll
    for (int k = 0; k < 64; ++k)
        a += Hs[r][k] * Ws[k * 16 + c];
    h2[(size_t)(blockIdx.x * 16 + r) * N_CLS + c] = a;
}

// ---------------------------------------------------------------------------
// SpMM2 (CSR) fused with log_softmax: 8 lanes per row (lane owns classes
// 2l,2l+1 as float2), 32 rows per block. 4-deep edge unroll.
// ---------------------------------------------------------------------------
__global__ __launch_bounds__(256) void spmm2_lsm_k(const int* __restrict__ rp,
                                                   const int2* __restrict__ edges2,
                                                   const float* __restrict__ h2,
                                                   float* __restrict__ outp) {
    const int l   = threadIdx.x & 7;                         // class pair 2l,2l+1
    const int row = blockIdx.x * 32 + (threadIdx.x >> 3);    // N_NODES = 3125*32
    const int beg = rp[row];
    const int end = rp[row + 1];
    const float2* h2v = (const float2*)h2;                   // row stride = 8

    float a0 = 0.f, a1 = 0.f;
    int i = beg;
    for (; i + 4 <= end; i += 4) {
        int2 e0 = edges2[i + 0], e1 = edges2[i + 1];
        int2 e2 = edges2[i + 2], e3 = edges2[i + 3];
        float2 g0 = h2v[(size_t)e0.x * 8 + l];
        float2 g1 = h2v[(size_t)e1.x * 8 + l];
        float2 g2 = h2v[(size_t)e2.x * 8 + l];
        float2 g3 = h2v[(size_t)e3.x * 8 + l];
        float v0 = __int_as_float(e0.y), v1 = __int_as_float(e1.y);
        float v2 = __int_as_float(e2.y), v3 = __int_as_float(e3.y);
        a0 += v0 * g0.x; a1 += v0 * g0.y;
        a0 += v1 * g1.x; a1 += v1 * g1.y;
        a0 += v2 * g2.x; a1 += v2 * g2.y;
        a0 += v3 * g3.x; a1 += v3 * g3.y;
    }
    for (; i < end; ++i) {
        int2 e = edges2[i];
        float2 g = h2v[(size_t)e.x * 8 + l];
        float v = __int_as_float(e.y);
        a0 += v * g.x; a1 += v * g.y;
    }

    float m = fmaxf(a0, a1);
    #pragma unroll
    for (int off = 4; off; off >>= 1) m = fmaxf(m, __shfl_xor(m, off, 8));
    float ex = expf(a0 - m) + expf(a1 - m);
    float s = ex;
    #pragma unroll
    for (int off = 4; off; off >>= 1) s += __shfl_xor(s, off, 8);
    float ls = logf(s);
    *(float2*)(outp + (size_t)row * N_CLS + 2 * l) =
        make_float2(a0 - m - ls, a1 - m - ls);
}

extern "C" void kernel_launch(void* const* d_in, const int* in_sizes, int n_in,
                              void* d_out, int out_size, void* d_ws, size_t ws_size,
                              hipStream_t stream) {
    const float* x        = (const float*)d_in[0];
    const int*   adj_row  = (const int*)d_in[1];
    const int*   adj_col  = (const int*)d_in[2];
    const float* adj_vals = (const float*)d_in[3];
    const float* W1       = (const float*)d_in[4];
    const float* b1       = (const float*)d_in[5];
    const float* W2       = (const float*)d_in[6];
    const float* b2       = (const float*)d_in[7];
    float*       out      = (float*)d_out;

    // Workspace (~58 MB): h0 fp32 | h2 fp32 | edges | edges2 | meta | w1f
    const size_t H0_BYTES = (size_t)N_NODES * N_HID * sizeof(float);   // 25.6 MB
    const size_t H2_BYTES = (size_t)N_NODES * N_CLS * sizeof(float);   // 6.4 MB
    const size_t E_BYTES  = (size_t)N_EDGES * sizeof(int2);            // 12.8 MB
    float* h0f    = (float*)d_ws;
    float* h2     = (float*)((char*)d_ws + H0_BYTES);
    int2*  edges  = (int2*)((char*)h2 + H2_BYTES);
    int2*  edges2 = (int2*)((char*)edges + E_BYTES);
    int*   bcnt   = (int*)((char*)edges2 + E_BYTES);   // NB
    int*   bbase  = bcnt + NB;                         // NB+1
    int*   gcur   = bbase + NB + 1;                    // NB
    int*   rp     = gcur + NB;                         // N_NODES+1
    bfraw* w1f    = (bfraw*)(rp + N_NODES + 1);        // 16384 bf16 (32 KB)

    // --- CSR build; gemm1 merged into the scatter dispatch ---
    hipMemsetAsync(bcnt, 0, NB * sizeof(int), stream);
    w1cvt_hist_k<<<320, 256, 0, stream>>>(W1, w1f, adj_row, bcnt);
    bscan_k<<<1, 512, 0, stream>>>(bcnt, bbase, gcur, rp);
    scatter_gemm1_k<<<NSCAT + NGEMM1, 256, 0, stream>>>(adj_row, adj_col, adj_vals,
                                                        gcur, edges,
                                                        x, w1f, b1, h0f);
    sort_k<<<NB, 256, 0, stream>>>(bbase, edges, edges2, rp);

    // --- layer 1 (spmm1 fused with relu + gemm2) ---
    spmm1_fused3_k<<<N_NODES / 16, 256, 0, stream>>>(rp, edges2, h0f, W2, b2, h2);

    // --- layer 2 ---
    spmm2_lsm_k<<<N_NODES / 32, 256, 0, stream>>>(rp, edges2, h2, out);
}

// Round 14
// 283.245 us; speedup vs baseline: 1.1858x; 1.1858x over previous
//
#include <hip/hip_runtime.h>

#define N_NODES 100000
#define N_EDGES 1600000
#define N_FEAT  256
#define N_HID   64
#define N_CLS   16
#define NB      391          // ceil(N_NODES/256) row buckets
#define CHUNK   8192         // edges per scatter block
#define NSCAT   196          // ceil(N_EDGES/CHUNK) scatter blocks
#define NGEMM1  1563         // ceil(N_NODES/64) gemm1 blocks

typedef unsigned short bfraw;
typedef unsigned int uint32;

typedef __attribute__((ext_vector_type(8))) short  bf16x8;
typedef __attribute__((ext_vector_type(4))) float  f32x4;

__device__ __forceinline__ bfraw f2bf(float f) {   // RNE
    union { float f; unsigned int i; } v; v.f = f;
    unsigned int x = v.i;
    return (bfraw)((x + 0x7FFFu + ((x >> 16) & 1u)) >> 16);
}

__device__ __forceinline__ float bf_lo(uint32 g) { return __uint_as_float(g << 16); }
__device__ __forceinline__ float bf_hi(uint32 g) { return __uint_as_float(g & 0xFFFF0000u); }

// ---------------------------------------------------------------------------
// Merged: blocks [0,64) pack W1 into B-fragment-order bf16 table;
// blocks [64,320) histogram rows into 256-row buckets (int4 edge loads).
// ---------------------------------------------------------------------------
__global__ __launch_bounds__(256) void w1cvt_hist_k(const float* __restrict__ W1,
                                                    bfraw* __restrict__ w1f,
                                                    const int* __restrict__ rowi,
                                                    int* __restrict__ bcnt) {
    __shared__ int lh[NB];
    if (blockIdx.x < 64) {
        int i = blockIdx.x * 256 + threadIdx.x;          // 16384 total
        int k = i >> 6, n = i & 63;
        w1f[((size_t)((k >> 3) * 64 + n) << 3) + (k & 7)] = f2bf(W1[i]);
        return;
    }
    for (int i = threadIdx.x; i < NB; i += 256) lh[i] = 0;
    __syncthreads();
    const int4* r4p = (const int4*)rowi;                 // N_EDGES/4 = 400000
    for (int i = (blockIdx.x - 64) * 256 + threadIdx.x; i < N_EDGES / 4; i += 256 * 256) {
        int4 r = r4p[i];
        atomicAdd(&lh[r.x >> 8], 1);
        atomicAdd(&lh[r.y >> 8], 1);
        atomicAdd(&lh[r.z >> 8], 1);
        atomicAdd(&lh[r.w >> 8], 1);
    }
    __syncthreads();
    for (int i = threadIdx.x; i < NB; i += 256) {
        int c = lh[i];
        if (c) atomicAdd(&bcnt[i], c);
    }
}

// exclusive scan of NB bucket counts -> bbase[0..NB], cursors; rp[N]=E
__global__ __launch_bounds__(512) void bscan_k(const int* __restrict__ bcnt,
                                               int* __restrict__ bbase,
                                               int* __restrict__ gcur,
                                               int* __restrict__ rp) {
    __shared__ int s[512];
    int t = threadIdx.x;
    int v = (t < NB) ? bcnt[t] : 0;
    s[t] = v;
    __syncthreads();
    #pragma unroll
    for (int off = 1; off < 512; off <<= 1) {
        int x = (t >= off) ? s[t - off] : 0;
        __syncthreads();
        s[t] += x;
        __syncthreads();
    }
    if (t <= NB) {
        int b = s[t] - v;              // exclusive prefix (v=0 at t==NB)
        bbase[t] = b;
        if (t < NB) gcur[t] = b;
    }
    if (t == 0) rp[N_NODES] = N_EDGES;
}

// ---------------------------------------------------------------------------
// Merged dispatch: blocks [0,NSCAT) scatter edges into bucket regions
// (int4-vectorized: thread's 32 edges loaded upfront, rows kept in regs
// across the barrier -> 8 loads in flight instead of scalar dependent
// chains); blocks [NSCAT,...) run GEMM1 (bf16 h0 output).
// ---------------------------------------------------------------------------
__global__ __launch_bounds__(256) void scatter_gemm1_k(const int* __restrict__ rowi,
                                                       const int* __restrict__ coli,
                                                       const float* __restrict__ vals,
                                                       int* __restrict__ gcur,
                                                       int2* __restrict__ edges,
                                                       const float* __restrict__ x,
                                                       const bfraw* __restrict__ w1f,
                                                       const float* __restrict__ b1,
                                                       bfraw* __restrict__ h0) {
    __shared__ int lh[NB];
    __shared__ int lb[NB];
    const int t = threadIdx.x;

    if (blockIdx.x < NSCAT) {
        // ---------------- scatter path ----------------
        const int e0   = blockIdx.x * CHUNK;
        const bool full = (e0 + CHUNK <= N_EDGES);
        for (int i = t; i < NB; i += 256) lh[i] = 0;
        __syncthreads();

        int4 r4[8];
        if (full) {
            const int4* rp4 = (const int4*)(rowi + e0);   // 16B-aligned (e0%8192==0)
            #pragma unroll
            for (int u = 0; u < 8; ++u) r4[u] = rp4[t + u * 256];
            #pragma unroll
            for (int u = 0; u < 8; ++u) {
                atomicAdd(&lh[r4[u].x >> 8], 1);
                atomicAdd(&lh[r4[u].y >> 8], 1);
                atomicAdd(&lh[r4[u].z >> 8], 1);
                atomicAdd(&lh[r4[u].w >> 8], 1);
            }
        } else {
            for (int j = t; j < CHUNK; j += 256) {
                int e = e0 + j;
                if (e < N_EDGES) atomicAdd(&lh[rowi[e] >> 8], 1);
            }
        }
        __syncthreads();
        for (int i = t; i < NB; i += 256) {
            int c = lh[i];
            lb[i] = c ? atomicAdd(&gcur[i], c) : 0;
            lh[i] = 0;                      // reuse as rank counter
        }
        __syncthreads();
        if (full) {
            const int4*   cp4 = (const int4*)(coli + e0);
            const float4* vp4 = (const float4*)(vals + e0);
            #pragma unroll
            for (int u = 0; u < 8; ++u) {
                int4   c4 = cp4[t + u * 256];
                float4 v4 = vp4[t + u * 256];
                int r, b, rk;
                r = r4[u].x; b = r >> 8; rk = atomicAdd(&lh[b], 1);
                edges[lb[b] + rk] = make_int2(c4.x | ((r & 255) << 17), __float_as_int(v4.x));
                r = r4[u].y; b = r >> 8; rk = atomicAdd(&lh[b], 1);
                edges[lb[b] + rk] = make_int2(c4.y | ((r & 255) << 17), __float_as_int(v4.y));
                r = r4[u].z; b = r >> 8; rk = atomicAdd(&lh[b], 1);
                edges[lb[b] + rk] = make_int2(c4.z | ((r & 255) << 17), __float_as_int(v4.z));
                r = r4[u].w; b = r >> 8; rk = atomicAdd(&lh[b], 1);
                edges[lb[b] + rk] = make_int2(c4.w | ((r & 255) << 17), __float_as_int(v4.w));
            }
        } else {
            for (int j = t; j < CHUNK; j += 256) {
                int e = e0 + j;
                if (e < N_EDGES) {
                    int r  = rowi[e];
                    int b  = r >> 8;
                    int rk = atomicAdd(&lh[b], 1);
                    edges[lb[b] + rk] = make_int2(coli[e] | ((r & 255) << 17),
                                                  __float_as_int(vals[e]));
                }
            }
        }
        return;
    }

    // ---------------- gemm1 path (bf16 h0 output) ----------------
    const int bg   = blockIdx.x - NSCAT;
    const int w    = t >> 6;
    const int lane = t & 63;
    const int q    = lane >> 4;
    const int m    = lane & 15;

    const int row  = bg * 64 + w * 16 + m;
    const int srow = row < N_NODES ? row : N_NODES - 1;
    const float* xp = x + (size_t)srow * N_FEAT + q * 8;
    const bf16x8* w1v = (const bf16x8*)w1f;

    f32x4 acc[4];
    #pragma unroll
    for (int nt = 0; nt < 4; ++nt) acc[nt] = (f32x4){0.f, 0.f, 0.f, 0.f};

    #pragma unroll
    for (int s = 0; s < 8; ++s) {
        float4 a0 = *(const float4*)(xp + s * 32);
        float4 a1 = *(const float4*)(xp + s * 32 + 4);
        bf16x8 af;
        af[0] = (short)f2bf(a0.x); af[1] = (short)f2bf(a0.y);
        af[2] = (short)f2bf(a0.z); af[3] = (short)f2bf(a0.w);
        af[4] = (short)f2bf(a1.x); af[5] = (short)f2bf(a1.y);
        af[6] = (short)f2bf(a1.z); af[7] = (short)f2bf(a1.w);
        const int g = s * 4 + q;                 // k-group (k = g*8)
        #pragma unroll
        for (int nt = 0; nt < 4; ++nt) {
            bf16x8 bf_ = w1v[g * 64 + nt * 16 + m];
            acc[nt] = __builtin_amdgcn_mfma_f32_16x16x32_bf16(af, bf_, acc[nt], 0, 0, 0);
        }
    }

    float bb[4];
    #pragma unroll
    for (int nt = 0; nt < 4; ++nt) bb[nt] = b1[nt * 16 + m];

    const int orow0 = bg * 64 + w * 16 + q * 4;
    #pragma unroll
    for (int r = 0; r < 4; ++r) {
        int orow = orow0 + r;
        if (orow < N_NODES) {
            bfraw* op = h0 + (size_t)orow * N_HID + m;
            #pragma unroll
            for (int nt = 0; nt < 4; ++nt)
                op[nt * 16] = f2bf(acc[nt][r] + bb[nt]);
        }
    }
}

// ---------------------------------------------------------------------------
// Per-bucket counting sort -> exact CSR (edges2, rp). One block per bucket.
// Both passes unrolled 4-deep (4 independent int2 loads in flight).
// ---------------------------------------------------------------------------
__global__ __launch_bounds__(256) void sort_k(const int* __restrict__ bbase,
                                              const int2* __restrict__ edges,
                                              int2* __restrict__ edges2,
                                              int* __restrict__ rp) {
    __shared__ int cnt[256];
    __shared__ int pos[256];
    const int t   = threadIdx.x;
    const int b   = blockIdx.x;
    const int beg = bbase[b];
    const int end = bbase[b + 1];

    cnt[t] = 0;
    __syncthreads();
    {
        int i = beg + t;
        for (; i + 768 < end; i += 1024) {
            int2 a = edges[i], c = edges[i + 256], d = edges[i + 512], e = edges[i + 768];
            atomicAdd(&cnt[(a.x >> 17) & 255], 1);
            atomicAdd(&cnt[(c.x >> 17) & 255], 1);
            atomicAdd(&cnt[(d.x >> 17) & 255], 1);
            atomicAdd(&cnt[(e.x >> 17) & 255], 1);
        }
        for (; i < end; i += 256)
            atomicAdd(&cnt[(edges[i].x >> 17) & 255], 1);
    }
    __syncthreads();

    int v = cnt[t];
    pos[t] = v;
    __syncthreads();
    #pragma unroll
    for (int off = 1; off < 256; off <<= 1) {
        int y = (t >= off) ? pos[t - off] : 0;
        __syncthreads();
        pos[t] += y;
        __syncthreads();
    }
    int excl = pos[t] - v;

    int row = (b << 8) + t;
    if (row < N_NODES) rp[row] = beg + excl;
    __syncthreads();
    pos[t] = excl;                             // cursor
    __syncthreads();

    {
        int i = beg + t;
        for (; i + 768 < end; i += 1024) {
            int2 E0 = edges[i], E1 = edges[i + 256], E2 = edges[i + 512], E3 = edges[i + 768];
            int r0 = (E0.x >> 17) & 255, r1 = (E1.x >> 17) & 255;
            int r2 = (E2.x >> 17) & 255, r3 = (E3.x >> 17) & 255;
            int k0 = atomicAdd(&pos[r0], 1);
            int k1 = atomicAdd(&pos[r1], 1);
            int k2 = atomicAdd(&pos[r2], 1);
            int k3 = atomicAdd(&pos[r3], 1);
            edges2[beg + k0] = make_int2(E0.x & 0x1FFFF, E0.y);
            edges2[beg + k1] = make_int2(E1.x & 0x1FFFF, E1.y);
            edges2[beg + k2] = make_int2(E2.x & 0x1FFFF, E2.y);
            edges2[beg + k3] = make_int2(E3.x & 0x1FFFF, E3.y);
        }
        for (; i < end; i += 256) {
            int2 E = edges[i];
            int r  = (E.x >> 17) & 255;
            int rk = atomicAdd(&pos[r], 1);
            edges2[beg + rk] = make_int2(E.x & 0x1FFFF, E.y);
        }
    }
}

// ---------------------------------------------------------------------------
// SpMM1 (CSR) fused with ReLU + GEMM2: one 16-lane group per row,
// 16 rows per block. Lane l gathers uint2 (bf16 features 4l..4l+3) per
// edge; 8 edges in flight per group. Epilogue: relu'd 16x64 tile in LDS,
// 256 threads compute tile @ W2 + b2.
// ---------------------------------------------------------------------------
__global__ __launch_bounds__(256) void spmm1_fused3_k(const int* __restrict__ rp,
                                                      const int2* __restrict__ edges2,
                                                      const uint32* __restrict__ h0p,
                                                      const float* __restrict__ W2,
                                                      const float* __restrict__ b2,
                                                      float* __restrict__ h2) {
    __shared__ float Hs[16][68];       // stride 68: float4-aligned rows, 2-way banks
    __shared__ float Ws[64 * 16];
    __shared__ float bs[16];
    const int t = threadIdx.x;
    *(float4*)&Ws[t * 4] = ((const float4*)W2)[t];
    if (t < 16) bs[t] = b2[t];

    const int g16 = t >> 4;            // group id = row within block
    const int l   = t & 15;            // lane in group: owns features 4l..4l+3
    const int row = blockIdx.x * 16 + g16;
    const int beg = rp[row];
    const int end = rp[row + 1];

    const uint2* h0v = (const uint2*)h0p;    // 8B = words 2l,2l+1 of a row

    float a0 = 0.f, a1 = 0.f, a2 = 0.f, a3 = 0.f;
    int i = beg;
    for (; i + 8 <= end; i += 8) {
        int2 E[8];
        #pragma unroll
        for (int u = 0; u < 8; ++u) E[u] = edges2[i + u];
        uint2 q[8];
        #pragma unroll
        for (int u = 0; u < 8; ++u) q[u] = h0v[(size_t)E[u].x * 16 + l];
        #pragma unroll
        for (int u = 0; u < 8; ++u) {
            float v = __int_as_float(E[u].y);
            a0 += v * bf_lo(q[u].x); a1 += v * bf_hi(q[u].x);
            a2 += v * bf_lo(q[u].y); a3 += v * bf_hi(q[u].y);
        }
    }
    for (; i + 4 <= end; i += 4) {
        int2 E[4];
        #pragma unroll
        for (int u = 0; u < 4; ++u) E[u] = edges2[i + u];
        uint2 q[4];
        #pragma unroll
        for (int u = 0; u < 4; ++u) q[u] = h0v[(size_t)E[u].x * 16 + l];
        #pragma unroll
        for (int u = 0; u < 4; ++u) {
            float v = __int_as_float(E[u].y);
            a0 += v * bf_lo(q[u].x); a1 += v * bf_hi(q[u].x);
            a2 += v * bf_lo(q[u].y); a3 += v * bf_hi(q[u].y);
        }
    }
    for (; i < end; ++i) {
        int2 E = edges2[i];
        uint2 q = h0v[(size_t)E.x * 16 + l];
        float v = __int_as_float(E.y);
        a0 += v * bf_lo(q.x); a1 += v * bf_hi(q.x);
        a2 += v * bf_lo(q.y); a3 += v * bf_hi(q.y);
    }

    *(float4*)&Hs[g16][4 * l] = make_float4(fmaxf(a0, 0.f), fmaxf(a1, 0.f),
                                            fmaxf(a2, 0.f), fmaxf(a3, 0.f));
    __syncthreads();

    // epilogue: h2[16][16] = Hs @ W2 + b2
    const int r = t >> 4;
    const int c = t & 15;
    float a = bs[c];
    #pragma unroll
    for (int k = 0; k < 64; ++k)
        a += Hs[r][k] * Ws[k * 16 + c];
    h2[(size_t)(blockIdx.x * 16 + r) * N_CLS + c] = a;
}

// ---------------------------------------------------------------------------
// SpMM2 (CSR) fused with log_softmax: 8 lanes per row (lane owns classes
// 2l,2l+1 as float2), 32 rows per block. 4-deep edge unroll.
// ---------------------------------------------------------------------------
__global__ __launch_bounds__(256) void spmm2_lsm_k(const int* __restrict__ rp,
                                                   const int2* __restrict__ edges2,
                                                   const float* __restrict__ h2,
                                                   float* __restrict__ outp) {
    const int l   = threadIdx.x & 7;                         // class pair 2l,2l+1
    const int row = blockIdx.x * 32 + (threadIdx.x >> 3);    // N_NODES = 3125*32
    const int beg = rp[row];
    const int end = rp[row + 1];
    const float2* h2v = (const float2*)h2;                   // row stride = 8

    float a0 = 0.f, a1 = 0.f;
    int i = beg;
    for (; i + 4 <= end; i += 4) {
        int2 e0 = edges2[i + 0], e1 = edges2[i + 1];
        int2 e2 = edges2[i + 2], e3 = edges2[i + 3];
        float2 g0 = h2v[(size_t)e0.x * 8 + l];
        float2 g1 = h2v[(size_t)e1.x * 8 + l];
        float2 g2 = h2v[(size_t)e2.x * 8 + l];
        float2 g3 = h2v[(size_t)e3.x * 8 + l];
        float v0 = __int_as_float(e0.y), v1 = __int_as_float(e1.y);
        float v2 = __int_as_float(e2.y), v3 = __int_as_float(e3.y);
        a0 += v0 * g0.x; a1 += v0 * g0.y;
        a0 += v1 * g1.x; a1 += v1 * g1.y;
        a0 += v2 * g2.x; a1 += v2 * g2.y;
        a0 += v3 * g3.x; a1 += v3 * g3.y;
    }
    for (; i < end; ++i) {
        int2 e = edges2[i];
        float2 g = h2v[(size_t)e.x * 8 + l];
        float v = __int_as_float(e.y);
        a0 += v * g.x; a1 += v * g.y;
    }

    float m = fmaxf(a0, a1);
    #pragma unroll
    for (int off = 4; off; off >>= 1) m = fmaxf(m, __shfl_xor(m, off, 8));
    float ex = expf(a0 - m) + expf(a1 - m);
    float s = ex;
    #pragma unroll
    for (int off = 4; off; off >>= 1) s += __shfl_xor(s, off, 8);
    float ls = logf(s);
    *(float2*)(outp + (size_t)row * N_CLS + 2 * l) =
        make_float2(a0 - m - ls, a1 - m - ls);
}

extern "C" void kernel_launch(void* const* d_in, const int* in_sizes, int n_in,
                              void* d_out, int out_size, void* d_ws, size_t ws_size,
                              hipStream_t stream) {
    const float* x        = (const float*)d_in[0];
    const int*   adj_row  = (const int*)d_in[1];
    const int*   adj_col  = (const int*)d_in[2];
    const float* adj_vals = (const float*)d_in[3];
    const float* W1       = (const float*)d_in[4];
    const float* b1       = (const float*)d_in[5];
    const float* W2       = (const float*)d_in[6];
    const float* b2       = (const float*)d_in[7];
    float*       out      = (float*)d_out;

    // Workspace (~46 MB): h0 bf16 | h2 fp32 | edges | edges2 | meta | w1f
    const size_t H0_BYTES = (size_t)N_NODES * N_HID * sizeof(bfraw);   // 12.8 MB
    const size_t H2_BYTES = (size_t)N_NODES * N_CLS * sizeof(float);   // 6.4 MB
    const size_t E_BYTES  = (size_t)N_EDGES * sizeof(int2);            // 12.8 MB
    bfraw* h0     = (bfraw*)d_ws;
    float* h2     = (float*)((char*)d_ws + H0_BYTES);
    int2*  edges  = (int2*)((char*)h2 + H2_BYTES);
    int2*  edges2 = (int2*)((char*)edges + E_BYTES);
    int*   bcnt   = (int*)((char*)edges2 + E_BYTES);   // NB
    int*   bbase  = bcnt + NB;                         // NB+1
    int*   gcur   = bbase + NB + 1;                    // NB
    int*   rp     = gcur + NB;                         // N_NODES+1
    bfraw* w1f    = (bfraw*)(rp + N_NODES + 1);        // 16384 bf16 (32 KB)

    // --- CSR build; gemm1 merged into the scatter dispatch ---
    hipMemsetAsync(bcnt, 0, NB * sizeof(int), stream);
    w1cvt_hist_k<<<320, 256, 0, stream>>>(W1, w1f, adj_row, bcnt);
    bscan_k<<<1, 512, 0, stream>>>(bcnt, bbase, gcur, rp);
    scatter_gemm1_k<<<NSCAT + NGEMM1, 256, 0, stream>>>(adj_row, adj_col, adj_vals,
                                                        gcur, edges,
                                                        x, w1f, b1, h0);
    sort_k<<<NB, 256, 0, stream>>>(bbase, edges, edges2, rp);

    // --- layer 1 (spmm1 fused with relu + gemm2) ---
    spmm1_fused3_k<<<N_NODES / 16, 256, 0, stream>>>(rp, edges2, (const uint32*)h0,
                                                     W2, b2, h2);

    // --- layer 2 ---
    spmm2_lsm_k<<<N_NODES / 32, 256, 0, stream>>>(rp, edges2, h2, out);
}

// Round 15
// 280.569 us; speedup vs baseline: 1.1971x; 1.0095x over previous
//
#include <hip/hip_runtime.h>

#define N_NODES 100000
#define N_EDGES 1600000
#define N_FEAT  256
#define N_HID   64
#define N_CLS   16
#define NB      391          // ceil(N_NODES/256) row buckets
#define CHUNK   8192         // edges per scatter block
#define NSCAT   196          // ceil(N_EDGES/CHUNK) scatter blocks
#define NGEMM1  1563         // ceil(N_NODES/64) gemm1 blocks
#define NHIST   256          // histogram blocks (partial-count rows)

typedef unsigned short bfraw;
typedef unsigned int uint32;

typedef __attribute__((ext_vector_type(8))) short  bf16x8;
typedef __attribute__((ext_vector_type(4))) float  f32x4;

__device__ __forceinline__ bfraw f2bf(float f) {   // RNE
    union { float f; unsigned int i; } v; v.f = f;
    unsigned int x = v.i;
    return (bfraw)((x + 0x7FFFu + ((x >> 16) & 1u)) >> 16);
}

__device__ __forceinline__ float bf_lo(uint32 g) { return __uint_as_float(g << 16); }
__device__ __forceinline__ float bf_hi(uint32 g) { return __uint_as_float(g & 0xFFFF0000u); }

// ---------------------------------------------------------------------------
// Merged: blocks [0,64) pack W1 into B-fragment-order bf16 table;
// blocks [64,320) histogram rows into 256-row buckets (int4 edge loads)
// and write ATOMIC-FREE partial counts part[hb][bucket] (every entry
// written -> no memset dispatch, no global atomics).
// ---------------------------------------------------------------------------
__global__ __launch_bounds__(256) void w1cvt_hist_k(const float* __restrict__ W1,
                                                    bfraw* __restrict__ w1f,
                                                    const int* __restrict__ rowi,
                                                    int* __restrict__ part) {
    __shared__ int lh[NB];
    if (blockIdx.x < 64) {
        int i = blockIdx.x * 256 + threadIdx.x;          // 16384 total
        int k = i >> 6, n = i & 63;
        w1f[((size_t)((k >> 3) * 64 + n) << 3) + (k & 7)] = f2bf(W1[i]);
        return;
    }
    const int hb = blockIdx.x - 64;                      // 0..255
    for (int i = threadIdx.x; i < NB; i += 256) lh[i] = 0;
    __syncthreads();
    const int4* r4p = (const int4*)rowi;                 // N_EDGES/4 = 400000
    for (int i = hb * 256 + threadIdx.x; i < N_EDGES / 4; i += 256 * 256) {
        int4 r = r4p[i];
        atomicAdd(&lh[r.x >> 8], 1);
        atomicAdd(&lh[r.y >> 8], 1);
        atomicAdd(&lh[r.z >> 8], 1);
        atomicAdd(&lh[r.w >> 8], 1);
    }
    __syncthreads();
    for (int i = threadIdx.x; i < NB; i += 256)
        part[hb * NB + i] = lh[i];                       // plain store
}

// exclusive scan: aggregate 256 partial rows (coalesced across threads),
// then scan -> bbase[0..NB], cursors; rp[N]=E
__global__ __launch_bounds__(512) void bscan_k(const int* __restrict__ part,
                                               int* __restrict__ bbase,
                                               int* __restrict__ gcur,
                                               int* __restrict__ rp) {
    __shared__ int s[512];
    int t = threadIdx.x;
    int v = 0;
    if (t < NB) {
        #pragma unroll 8
        for (int hb = 0; hb < NHIST; ++hb) v += part[hb * NB + t];
    }
    s[t] = v;
    __syncthreads();
    #pragma unroll
    for (int off = 1; off < 512; off <<= 1) {
        int x = (t >= off) ? s[t - off] : 0;
        __syncthreads();
        s[t] += x;
        __syncthreads();
    }
    if (t <= NB) {
        int b = s[t] - v;              // exclusive prefix (v=0 at t==NB)
        bbase[t] = b;
        if (t < NB) gcur[t] = b;
    }
    if (t == 0) rp[N_NODES] = N_EDGES;
}

// ---------------------------------------------------------------------------
// Merged dispatch: blocks [0,NSCAT) scatter edges (int4-vectorized, rows
// registered across the barrier); blocks [NSCAT,...) run GEMM1 with ALL
// x-loads prefetched upfront (16 float4 in flight vs 2 -> hides HBM lat).
// ---------------------------------------------------------------------------
__global__ __launch_bounds__(256) void scatter_gemm1_k(const int* __restrict__ rowi,
                                                       const int* __restrict__ coli,
                                                       const float* __restrict__ vals,
                                                       int* __restrict__ gcur,
                                                       int2* __restrict__ edges,
                                                       const float* __restrict__ x,
                                                       const bfraw* __restrict__ w1f,
                                                       const float* __restrict__ b1,
                                                       bfraw* __restrict__ h0) {
    __shared__ int lh[NB];
    __shared__ int lb[NB];
    const int t = threadIdx.x;

    if (blockIdx.x < NSCAT) {
        // ---------------- scatter path ----------------
        const int e0   = blockIdx.x * CHUNK;
        const bool full = (e0 + CHUNK <= N_EDGES);
        for (int i = t; i < NB; i += 256) lh[i] = 0;
        __syncthreads();

        int4 r4[8];
        if (full) {
            const int4* rp4 = (const int4*)(rowi + e0);   // 16B-aligned (e0%8192==0)
            #pragma unroll
            for (int u = 0; u < 8; ++u) r4[u] = rp4[t + u * 256];
            #pragma unroll
            for (int u = 0; u < 8; ++u) {
                atomicAdd(&lh[r4[u].x >> 8], 1);
                atomicAdd(&lh[r4[u].y >> 8], 1);
                atomicAdd(&lh[r4[u].z >> 8], 1);
                atomicAdd(&lh[r4[u].w >> 8], 1);
            }
        } else {
            for (int j = t; j < CHUNK; j += 256) {
                int e = e0 + j;
                if (e < N_EDGES) atomicAdd(&lh[rowi[e] >> 8], 1);
            }
        }
        __syncthreads();
        for (int i = t; i < NB; i += 256) {
            int c = lh[i];
            lb[i] = c ? atomicAdd(&gcur[i], c) : 0;
            lh[i] = 0;                      // reuse as rank counter
        }
        __syncthreads();
        if (full) {
            const int4*   cp4 = (const int4*)(coli + e0);
            const float4* vp4 = (const float4*)(vals + e0);
            #pragma unroll
            for (int u = 0; u < 8; ++u) {
                int4   c4 = cp4[t + u * 256];
                float4 v4 = vp4[t + u * 256];
                int r, b, rk;
                r = r4[u].x; b = r >> 8; rk = atomicAdd(&lh[b], 1);
                edges[lb[b] + rk] = make_int2(c4.x | ((r & 255) << 17), __float_as_int(v4.x));
                r = r4[u].y; b = r >> 8; rk = atomicAdd(&lh[b], 1);
                edges[lb[b] + rk] = make_int2(c4.y | ((r & 255) << 17), __float_as_int(v4.y));
                r = r4[u].z; b = r >> 8; rk = atomicAdd(&lh[b], 1);
                edges[lb[b] + rk] = make_int2(c4.z | ((r & 255) << 17), __float_as_int(v4.z));
                r = r4[u].w; b = r >> 8; rk = atomicAdd(&lh[b], 1);
                edges[lb[b] + rk] = make_int2(c4.w | ((r & 255) << 17), __float_as_int(v4.w));
            }
        } else {
            for (int j = t; j < CHUNK; j += 256) {
                int e = e0 + j;
                if (e < N_EDGES) {
                    int r  = rowi[e];
                    int b  = r >> 8;
                    int rk = atomicAdd(&lh[b], 1);
                    edges[lb[b] + rk] = make_int2(coli[e] | ((r & 255) << 17),
                                                  __float_as_int(vals[e]));
                }
            }
        }
        return;
    }

    // ---------------- gemm1 path (x fully prefetched) ----------------
    const int bg   = blockIdx.x - NSCAT;
    const int w    = t >> 6;
    const int lane = t & 63;
    const int q    = lane >> 4;
    const int m    = lane & 15;

    const int row  = bg * 64 + w * 16 + m;
    const int srow = row < N_NODES ? row : N_NODES - 1;
    const float* xp = x + (size_t)srow * N_FEAT + q * 8;
    const bf16x8* w1v = (const bf16x8*)w1f;

    float4 x0[8], x1[8];                     // all 16 loads issued upfront
    #pragma unroll
    for (int s = 0; s < 8; ++s) {
        x0[s] = *(const float4*)(xp + s * 32);
        x1[s] = *(const float4*)(xp + s * 32 + 4);
    }

    f32x4 acc[4];
    #pragma unroll
    for (int nt = 0; nt < 4; ++nt) acc[nt] = (f32x4){0.f, 0.f, 0.f, 0.f};

    #pragma unroll
    for (int s = 0; s < 8; ++s) {
        bf16x8 af;
        af[0] = (short)f2bf(x0[s].x); af[1] = (short)f2bf(x0[s].y);
        af[2] = (short)f2bf(x0[s].z); af[3] = (short)f2bf(x0[s].w);
        af[4] = (short)f2bf(x1[s].x); af[5] = (short)f2bf(x1[s].y);
        af[6] = (short)f2bf(x1[s].z); af[7] = (short)f2bf(x1[s].w);
        const int g = s * 4 + q;                 // k-group (k = g*8)
        #pragma unroll
        for (int nt = 0; nt < 4; ++nt) {
            bf16x8 bf_ = w1v[g * 64 + nt * 16 + m];
            acc[nt] = __builtin_amdgcn_mfma_f32_16x16x32_bf16(af, bf_, acc[nt], 0, 0, 0);
        }
    }

    float bb[4];
    #pragma unroll
    for (int nt = 0; nt < 4; ++nt) bb[nt] = b1[nt * 16 + m];

    const int orow0 = bg * 64 + w * 16 + q * 4;
    #pragma unroll
    for (int r = 0; r < 4; ++r) {
        int orow = orow0 + r;
        if (orow < N_NODES) {
            bfraw* op = h0 + (size_t)orow * N_HID + m;
            #pragma unroll
            for (int nt = 0; nt < 4; ++nt)
                op[nt * 16] = f2bf(acc[nt][r] + bb[nt]);
        }
    }
}

// ---------------------------------------------------------------------------
// Per-bucket counting sort -> exact CSR (edges2, rp). One block per bucket.
// Both passes unrolled 4-deep (4 independent int2 loads in flight).
// ---------------------------------------------------------------------------
__global__ __launch_bounds__(256) void sort_k(const int* __restrict__ bbase,
                                              const int2* __restrict__ edges,
                                              int2* __restrict__ edges2,
                                              int* __restrict__ rp) {
    __shared__ int cnt[256];
    __shared__ int pos[256];
    const int t   = threadIdx.x;
    const int b   = blockIdx.x;
    const int beg = bbase[b];
    const int end = bbase[b + 1];

    cnt[t] = 0;
    __syncthreads();
    {
        int i = beg + t;
        for (; i + 768 < end; i += 1024) {
            int2 a = edges[i], c = edges[i + 256], d = edges[i + 512], e = edges[i + 768];
            atomicAdd(&cnt[(a.x >> 17) & 255], 1);
            atomicAdd(&cnt[(c.x >> 17) & 255], 1);
            atomicAdd(&cnt[(d.x >> 17) & 255], 1);
            atomicAdd(&cnt[(e.x >> 17) & 255], 1);
        }
        for (; i < end; i += 256)
            atomicAdd(&cnt[(edges[i].x >> 17) & 255], 1);
    }
    __syncthreads();

    int v = cnt[t];
    pos[t] = v;
    __syncthreads();
    #pragma unroll
    for (int off = 1; off < 256; off <<= 1) {
        int y = (t >= off) ? pos[t - off] : 0;
        __syncthreads();
        pos[t] += y;
        __syncthreads();
    }
    int excl = pos[t] - v;

    int row = (b << 8) + t;
    if (row < N_NODES) rp[row] = beg + excl;
    __syncthreads();
    pos[t] = excl;                             // cursor
    __syncthreads();

    {
        int i = beg + t;
        for (; i + 768 < end; i += 1024) {
            int2 E0 = edges[i], E1 = edges[i + 256], E2 = edges[i + 512], E3 = edges[i + 768];
            int r0 = (E0.x >> 17) & 255, r1 = (E1.x >> 17) & 255;
            int r2 = (E2.x >> 17) & 255, r3 = (E3.x >> 17) & 255;
            int k0 = atomicAdd(&pos[r0], 1);
            int k1 = atomicAdd(&pos[r1], 1);
            int k2 = atomicAdd(&pos[r2], 1);
            int k3 = atomicAdd(&pos[r3], 1);
            edges2[beg + k0] = make_int2(E0.x & 0x1FFFF, E0.y);
            edges2[beg + k1] = make_int2(E1.x & 0x1FFFF, E1.y);
            edges2[beg + k2] = make_int2(E2.x & 0x1FFFF, E2.y);
            edges2[beg + k3] = make_int2(E3.x & 0x1FFFF, E3.y);
        }
        for (; i < end; i += 256) {
            int2 E = edges[i];
            int r  = (E.x >> 17) & 255;
            int rk = atomicAdd(&pos[r], 1);
            edges2[beg + rk] = make_int2(E.x & 0x1FFFF, E.y);
        }
    }
}

// ---------------------------------------------------------------------------
// SpMM1 (CSR) fused with ReLU + GEMM2: one 16-lane group per row,
// 16 rows per block. Lane l gathers uint2 (bf16 features 4l..4l+3) per
// edge; 8 edges in flight per group. Epilogue: relu'd 16x64 tile in LDS,
// 256 threads compute tile @ W2 + b2.
// ---------------------------------------------------------------------------
__global__ __launch_bounds__(256) void spmm1_fused3_k(const int* __restrict__ rp,
                                                      const int2* __restrict__ edges2,
                                                      const uint32* __restrict__ h0p,
                                                      const float* __restrict__ W2,
                                                      const float* __restrict__ b2,
                                                      float* __restrict__ h2) {
    __shared__ float Hs[16][68];       // stride 68: float4-aligned rows, 2-way banks
    __shared__ float Ws[64 * 16];
    __shared__ float bs[16];
    const int t = threadIdx.x;
    *(float4*)&Ws[t * 4] = ((const float4*)W2)[t];
    if (t < 16) bs[t] = b2[t];

    const int g16 = t >> 4;            // group id = row within block
    const int l   = t & 15;            // lane in group: owns features 4l..4l+3
    const int row = blockIdx.x * 16 + g16;
    const int beg = rp[row];
    const int end = rp[row + 1];

    const uint2* h0v = (const uint2*)h0p;    // 8B = words 2l,2l+1 of a row

    float a0 = 0.f, a1 = 0.f, a2 = 0.f, a3 = 0.f;
    int i = beg;
    for (; i + 8 <= end; i += 8) {
        int2 E[8];
        #pragma unroll
        for (int u = 0; u < 8; ++u) E[u] = edges2[i + u];
        uint2 q[8];
        #pragma unroll
        for (int u = 0; u < 8; ++u) q[u] = h0v[(size_t)E[u].x * 16 + l];
        #pragma unroll
        for (int u = 0; u < 8; ++u) {
            float v = __int_as_float(E[u].y);
            a0 += v * bf_lo(q[u].x); a1 += v * bf_hi(q[u].x);
            a2 += v * bf_lo(q[u].y); a3 += v * bf_hi(q[u].y);
        }
    }
    for (; i + 4 <= end; i += 4) {
        int2 E[4];
        #pragma unroll
        for (int u = 0; u < 4; ++u) E[u] = edges2[i + u];
        uint2 q[4];
        #pragma unroll
        for (int u = 0; u < 4; ++u) q[u] = h0v[(size_t)E[u].x * 16 + l];
        #pragma unroll
        for (int u = 0; u < 4; ++u) {
            float v = __int_as_float(E[u].y);
            a0 += v * bf_lo(q[u].x); a1 += v * bf_hi(q[u].x);
            a2 += v * bf_lo(q[u].y); a3 += v * bf_hi(q[u].y);
        }
    }
    for (; i < end; ++i) {
        int2 E = edges2[i];
        uint2 q = h0v[(size_t)E.x * 16 + l];
        float v = __int_as_float(E.y);
        a0 += v * bf_lo(q.x); a1 += v * bf_hi(q.x);
        a2 += v * bf_lo(q.y); a3 += v * bf_hi(q.y);
    }

    *(float4*)&Hs[g16][4 * l] = make_float4(fmaxf(a0, 0.f), fmaxf(a1, 0.f),
                                            fmaxf(a2, 0.f), fmaxf(a3, 0.f));
    __syncthreads();

    // epilogue: h2[16][16] = Hs @ W2 + b2
    const int r = t >> 4;
    const int c = t & 15;
    float a = bs[c];
    #pragma unroll
    for (int k = 0; k < 64; ++k)
        a += Hs[r][k] * Ws[k * 16 + c];
    h2[(size_t)(blockIdx.x * 16 + r) * N_CLS + c] = a;
}

// ---------------------------------------------------------------------------
// SpMM2 (CSR) fused with log_softmax: 8 lanes per row (lane owns classes
// 2l,2l+1 as float2), 32 rows per block. 8-deep edge unroll.
// ---------------------------------------------------------------------------
__global__ __launch_bounds__(256) void spmm2_lsm_k(const int* __restrict__ rp,
                                                   const int2* __restrict__ edges2,
                                                   const float* __restrict__ h2,
                                                   float* __restrict__ outp) {
    const int l   = threadIdx.x & 7;                         // class pair 2l,2l+1
    const int row = blockIdx.x * 32 + (threadIdx.x >> 3);    // N_NODES = 3125*32
    const int beg = rp[row];
    const int end = rp[row + 1];
    const float2* h2v = (const float2*)h2;                   // row stride = 8

    float a0 = 0.f, a1 = 0.f;
    int i = beg;
    for (; i + 8 <= end; i += 8) {
        int2 e[8];
        #pragma unroll
        for (int u = 0; u < 8; ++u) e[u] = edges2[i + u];
        float2 g[8];
        #pragma unroll
        for (int u = 0; u < 8; ++u) g[u] = h2v[(size_t)e[u].x * 8 + l];
        #pragma unroll
        for (int u = 0; u < 8; ++u) {
            float v = __int_as_float(e[u].y);
            a0 += v * g[u].x; a1 += v * g[u].y;
        }
    }
    for (; i + 4 <= end; i += 4) {
        int2 e[4];
        #pragma unroll
        for (int u = 0; u < 4; ++u) e[u] = edges2[i + u];
        float2 g[4];
        #pragma unroll
        for (int u = 0; u < 4; ++u) g[u] = h2v[(size_t)e[u].x * 8 + l];
        #pragma unroll
        for (int u = 0; u < 4; ++u) {
            float v = __int_as_float(e[u].y);
            a0 += v * g[u].x; a1 += v * g[u].y;
        }
    }
    for (; i < end; ++i) {
        int2 e = edges2[i];
        float2 g = h2v[(size_t)e.x * 8 + l];
        float v = __int_as_float(e.y);
        a0 += v * g.x; a1 += v * g.y;
    }

    float m = fmaxf(a0, a1);
    #pragma unroll
    for (int off = 4; off; off >>= 1) m = fmaxf(m, __shfl_xor(m, off, 8));
    float ex = expf(a0 - m) + expf(a1 - m);
    float s = ex;
    #pragma unroll
    for (int off = 4; off; off >>= 1) s += __shfl_xor(s, off, 8);
    float ls = logf(s);
    *(float2*)(outp + (size_t)row * N_CLS + 2 * l) =
        make_float2(a0 - m - ls, a1 - m - ls);
}

extern "C" void kernel_launch(void* const* d_in, const int* in_sizes, int n_in,
                              void* d_out, int out_size, void* d_ws, size_t ws_size,
                              hipStream_t stream) {
    const float* x        = (const float*)d_in[0];
    const int*   adj_row  = (const int*)d_in[1];
    const int*   adj_col  = (const int*)d_in[2];
    const float* adj_vals = (const float*)d_in[3];
    const float* W1       = (const float*)d_in[4];
    const float* b1       = (const float*)d_in[5];
    const float* W2       = (const float*)d_in[6];
    const float* b2       = (const float*)d_in[7];
    float*       out      = (float*)d_out;

    // Workspace (~47 MB): h0 bf16 | h2 fp32 | edges | edges2 | meta | w1f | part
    const size_t H0_BYTES = (size_t)N_NODES * N_HID * sizeof(bfraw);   // 12.8 MB
    const size_t H2_BYTES = (size_t)N_NODES * N_CLS * sizeof(float);   // 6.4 MB
    const size_t E_BYTES  = (size_t)N_EDGES * sizeof(int2);            // 12.8 MB
    bfraw* h0     = (bfraw*)d_ws;
    float* h2     = (float*)((char*)d_ws + H0_BYTES);
    int2*  edges  = (int2*)((char*)h2 + H2_BYTES);
    int2*  edges2 = (int2*)((char*)edges + E_BYTES);
    int*   bbase  = (int*)((char*)edges2 + E_BYTES);   // NB+1
    int*   gcur   = bbase + NB + 1;                    // NB
    int*   rp     = gcur + NB;                         // N_NODES+1
    bfraw* w1f    = (bfraw*)(rp + N_NODES + 1);        // 16384 bf16 (32 KB)
    int*   part   = (int*)(w1f + 16384);               // NHIST*NB (400 KB)

    // --- CSR build (no memset: atomic-free partial-count histogram) ---
    w1cvt_hist_k<<<320, 256, 0, stream>>>(W1, w1f, adj_row, part);
    bscan_k<<<1, 512, 0, stream>>>(part, bbase, gcur, rp);
    scatter_gemm1_k<<<NSCAT + NGEMM1, 256, 0, stream>>>(adj_row, adj_col, adj_vals,
                                                        gcur, edges,
                                                        x, w1f, b1, h0);
    sort_k<<<NB, 256, 0, stream>>>(bbase, edges, edges2, rp);

    // --- layer 1 (spmm1 fused with relu + gemm2) ---
    spmm1_fused3_k<<<N_NODES / 16, 256, 0, stream>>>(rp, edges2, (const uint32*)h0,
                                                     W2, b2, h2);

    // --- layer 2 ---
    spmm2_lsm_k<<<N_NODES / 32, 256, 0, stream>>>(rp, edges2, h2, out);
}